// Round 2
// baseline (321.444 us; speedup 1.0000x reference)
//
#include <hip/hip_runtime.h>
#include <hip/hip_bf16.h>
#include <math.h>

#define SEQ 4096
#define EMB 1024
#define NH  16
#define DK  64

typedef __attribute__((ext_vector_type(8))) unsigned short us8;
typedef __attribute__((ext_vector_type(8))) short         s8;
typedef __attribute__((ext_vector_type(4))) unsigned short us4;
typedef __attribute__((ext_vector_type(4))) float          f4;

static __device__ __forceinline__ unsigned short f2bf(float f) {
    union { float f; unsigned u; } v; v.f = f;
    unsigned r = v.u + 0x7FFF + ((v.u >> 16) & 1);
    return (unsigned short)(r >> 16);
}

__device__ __forceinline__ void gl2lds16(const void* g, void* l) {
    __builtin_amdgcn_global_load_lds((const __attribute__((address_space(1))) void*)g,
                                     (__attribute__((address_space(3))) void*)l, 16, 0, 0);
}

// pack two fp32 -> one dword of two truncated bf16 (hi = a, lo = b): one v_perm_b32
__device__ __forceinline__ int pkbf(float a, float b) {
    return (int)__builtin_amdgcn_perm(__float_as_uint(a), __float_as_uint(b), 0x07060302u);
}

// ---------------- fp32 -> bf16 convert, all 5 tensors in one launch ----------------
__global__ void cvt_all(const float* __restrict__ x,
                        const float* __restrict__ w0, const float* __restrict__ w1,
                        const float* __restrict__ w2, const float* __restrict__ w3,
                        unsigned short* __restrict__ xo,
                        unsigned short* __restrict__ o0, unsigned short* __restrict__ o1,
                        unsigned short* __restrict__ o2, unsigned short* __restrict__ o3) {
    const int idx = blockIdx.x * 256 + threadIdx.x;
    const float* in;
    unsigned short* out;
    int off;
    if (idx < (1 << 20)) { in = x; out = xo; off = idx; }
    else {
        const int t = idx - (1 << 20);
        const int w = t >> 18;
        off = t & ((1 << 18) - 1);
        in  = w == 0 ? w0 : (w == 1 ? w1 : (w == 2 ? w2 : w3));
        out = w == 0 ? o0 : (w == 1 ? o1 : (w == 2 ? o2 : o3));
    }
    const float4 v = ((const float4*)in)[off];
    us4 o;
    o[0] = f2bf(v.x); o[1] = f2bf(v.y); o[2] = f2bf(v.z); o[3] = f2bf(v.w);
    ((us4*)out)[off] = o;
}

// ---------------- bf16 64x64 transpose with k-permuted output columns ----------------
// pos(k): k=a*16+b*4+c -> (a>>1)*32 + b*8 + (a&1)*4 + c  (matches attn PV frag layout)
__global__ __launch_bounds__(256) void transpose_kernel(
    const unsigned short* __restrict__ in, unsigned short* __restrict__ out) {
    __shared__ unsigned short t[64][72];
    const int tid = threadIdx.x;
    const int row = tid >> 2, c = (tid & 3) * 16;
    const int gr = blockIdx.x * 64, gc = blockIdx.y * 64;
    const unsigned short* src = in + (size_t)(gr + row) * EMB + gc + c;
    *(us8*)&t[row][c]     = *(const us8*)src;
    *(us8*)&t[row][c + 8] = *(const us8*)(src + 8);
    __syncthreads();
    us8 o0, o1;
#pragma unroll
    for (int j = 0; j < 8; ++j) { o0[j] = t[c + j][row]; o1[j] = t[c + 8 + j][row]; }
    const int a_   = c >> 4;
    const int base = (a_ >> 1) * 32 + (a_ & 1) * 4;
    us4 g0, g1, g2, g3;
#pragma unroll
    for (int i = 0; i < 4; ++i) { g0[i] = o0[i]; g1[i] = o0[4 + i]; g2[i] = o1[i]; g3[i] = o1[4 + i]; }
    unsigned short* dst = out + (size_t)(gc + row) * SEQ + gr + base;
    *(us4*)dst        = g0;
    *(us4*)(dst + 8)  = g1;
    *(us4*)(dst + 16) = g2;
    *(us4*)(dst + 24) = g3;
}

// ---------------- fused QKV projection GEMM, 128x128 tile ----------------
__global__ __launch_bounds__(256) void qkv_gemm(
    const unsigned short* __restrict__ X,
    const unsigned short* __restrict__ Wq, const unsigned short* __restrict__ Wk,
    const unsigned short* __restrict__ Wv,
    const float* __restrict__ bq, const float* __restrict__ bk, const float* __restrict__ bv,
    unsigned short* __restrict__ Qo, unsigned short* __restrict__ Ko, unsigned short* __restrict__ Vo)
{
    __shared__ unsigned short As[128 * 64];
    __shared__ unsigned short Bs[128 * 64];

    const int region = blockIdx.y >> 3;
    const unsigned short* W   = region == 0 ? Wq : (region == 1 ? Wk : Wv);
    const float*         bias = region == 0 ? bq : (region == 1 ? bk : bv);
    unsigned short*      out  = region == 0 ? Qo : (region == 1 ? Ko : Vo);
    const float scale = region == 0 ? 0.18033688011112042f : 1.0f;   // 0.125 * log2(e)

    const int tid  = threadIdx.x;
    const int wave = tid >> 6;
    const int lane = tid & 63;
    const int quad = lane >> 4;
    const int l16  = lane & 15;
    const int wm   = (wave >> 1) * 64;
    const int wn   = (wave & 1) * 64;
    const int bm   = blockIdx.x * 128;
    const int bn   = (blockIdx.y & 7) * 128;

    f4 acc[4][4];
#pragma unroll
    for (int a = 0; a < 4; ++a)
#pragma unroll
        for (int b = 0; b < 4; ++b) acc[a][b] = (f4){0, 0, 0, 0};

    const int rsub = lane >> 3;
    const int gc   = ((lane & 7) ^ rsub) * 8;
    const int swz  = l16 & 7;

    for (int k0 = 0; k0 < EMB; k0 += 64) {
        __syncthreads();
#pragma unroll
        for (int i = 0; i < 4; ++i) {
            const int cb = i * 4 + wave;
            const int r  = cb * 8 + rsub;
            gl2lds16(X + (size_t)(bm + r) * EMB + k0 + gc, &As[cb * 512]);
            gl2lds16(W + (size_t)(bn + r) * EMB + k0 + gc, &Bs[cb * 512]);
        }
        __syncthreads();
#pragma unroll
        for (int kc = 0; kc < 2; ++kc) {
            s8 af[4], bf[4];
#pragma unroll
            for (int t = 0; t < 4; ++t) {
                const int seg = (kc * 4 + quad) ^ swz;
                af[t] = *(const s8*)&As[(wm + t * 16 + l16) * 64 + seg * 8];
                bf[t] = *(const s8*)&Bs[(wn + t * 16 + l16) * 64 + seg * 8];
            }
#pragma unroll
            for (int tm = 0; tm < 4; ++tm)
#pragma unroll
                for (int tn = 0; tn < 4; ++tn)
                    acc[tm][tn] = __builtin_amdgcn_mfma_f32_16x16x32_bf16(af[tm], bf[tn], acc[tm][tn], 0, 0, 0);
        }
    }

#pragma unroll
    for (int tn = 0; tn < 4; ++tn) {
        const int n = bn + wn + tn * 16 + l16;
        const float bv2 = bias[n];
#pragma unroll
        for (int tm = 0; tm < 4; ++tm)
#pragma unroll
            for (int rr = 0; rr < 4; ++rr) {
                const int m = bm + wm + tm * 16 + quad * 4 + rr;
                out[(size_t)m * EMB + n] = f2bf((acc[tm][tn][rr] + bv2) * scale);
            }
    }
}

// ---------------- output projection GEMM, 128x64 tile, fp32 out ----------------
__global__ __launch_bounds__(256) void gemm_op(
    const unsigned short* __restrict__ A, const unsigned short* __restrict__ B,
    const float* __restrict__ bias, float* __restrict__ C)
{
    __shared__ unsigned short As[128 * 64];
    __shared__ unsigned short Bs[64 * 64];

    const int tid  = threadIdx.x;
    const int wave = tid >> 6;
    const int lane = tid & 63;
    const int quad = lane >> 4;
    const int l16  = lane & 15;
    const int wm   = (wave >> 1) * 64;
    const int wn   = (wave & 1) * 32;
    const int bm   = blockIdx.x * 128;
    const int bn   = blockIdx.y * 64;

    f4 acc[4][2];
#pragma unroll
    for (int a = 0; a < 4; ++a) { acc[a][0] = (f4){0,0,0,0}; acc[a][1] = (f4){0,0,0,0}; }

    const int rsub = lane >> 3;
    const int gc   = ((lane & 7) ^ rsub) * 8;
    const int swz  = l16 & 7;

    for (int k0 = 0; k0 < EMB; k0 += 64) {
        __syncthreads();
#pragma unroll
        for (int i = 0; i < 6; ++i) {
            const int cb = i * 4 + wave;
            if (cb < 16) {
                gl2lds16(A + (size_t)(bm + cb * 8 + rsub) * EMB + k0 + gc, &As[cb * 512]);
            } else {
                const int c2 = cb - 16;
                gl2lds16(B + (size_t)(bn + c2 * 8 + rsub) * EMB + k0 + gc, &Bs[c2 * 512]);
            }
        }
        __syncthreads();
#pragma unroll
        for (int kc = 0; kc < 2; ++kc) {
            const int seg = (kc * 4 + quad) ^ swz;
            s8 af[4], bf[2];
#pragma unroll
            for (int t = 0; t < 4; ++t)
                af[t] = *(const s8*)&As[(wm + t * 16 + l16) * 64 + seg * 8];
#pragma unroll
            for (int t = 0; t < 2; ++t)
                bf[t] = *(const s8*)&Bs[(wn + t * 16 + l16) * 64 + seg * 8];
#pragma unroll
            for (int tm = 0; tm < 4; ++tm)
#pragma unroll
                for (int tn = 0; tn < 2; ++tn)
                    acc[tm][tn] = __builtin_amdgcn_mfma_f32_16x16x32_bf16(af[tm], bf[tn], acc[tm][tn], 0, 0, 0);
        }
    }

#pragma unroll
    for (int tn = 0; tn < 2; ++tn) {
        const int n = bn + wn + tn * 16 + l16;
        const float bv2 = bias[n];
#pragma unroll
        for (int tm = 0; tm < 4; ++tm)
#pragma unroll
            for (int rr = 0; rr < 4; ++rr) {
                const int m = bm + wm + tm * 16 + quad * 4 + rr;
                C[(size_t)m * EMB + n] = acc[tm][tn][rr] + bv2;
            }
    }
}

// ---------------- Flash attention (causal): two-phase full-utilization ----------------
// Q,K: bf16 [SEQ][EMB] (Q pre-scaled 0.125*log2e). Vt: bf16 [EMB][SEQ], k-permuted cols.
// 512 1-D blocks (XCD-bijective swizzle -> 2 heads per XCD L2), 8 waves.
// Tiles {A=63-u, B=u} per block; staging streams K j-pairs (K only in LDS, 32KB,
// XOR-swizzled). V is read DIRECT from global (L2-resident; LDS V-sharing was only
// 2-way so direct reads halve the DS pipe at acceptable L2 cost).
// LOW phase (j <= ~u): 8 waves = {tile} x {qh: 32q half} x {par: j parity} (prev scheme).
// TRANSITION: tile B done -> par-pair merge via LDS, normalize, store; B-waves re-arm
// as tile-A 16-row quarter waves on the odd-j stream. A-waves continue their o[par]
// accumulator (their high quarter == one of their two existing 16-row accumulators;
// par==1 waves swap o0<->o1 so high phase uniformly accumulates o0/l0).
// HIGH phase (j to 63-u): 8 waves = 4 quarters x 2 j-parities, all busy -> wave
// utilization ~51% -> ~98%. Epilogue merges {continued, frozen partner, B-high} per
// 16-row quarter. Fixed-max softmax, exp2 domain, zero-shfl PV, setprio on MFMA (T5).
__global__ __launch_bounds__(512, 4) void attn_kernel(
    const unsigned short* __restrict__ Qg, const unsigned short* __restrict__ Kg,
    const unsigned short* __restrict__ Vtg, unsigned short* __restrict__ Og)
{
    __shared__ unsigned short Ks[2][2][64][64];   // [buf][j&1][row][col^swz]  32KB
    __shared__ float mO[8][64][16];               // 8 half-slots x 64 lanes x 16f  32KB
    __shared__ float mL[8][64];                   // per-half-slot l partials   2KB

    const int tid  = threadIdx.x;
    const int wave = tid >> 6;
    const int lane = tid & 63;
    const int quad = lane >> 4;
    const int l16  = lane & 15;

    // XCD-bijective swizzle: 512 blocks, 8 XCDs -> 64 consecutive works per XCD (2 heads)
    const int n      = blockIdx.x;
    const int workid = (n & 7) * 64 + (n >> 3);
    const int h      = workid >> 5;
    const int y      = workid & 31;
    const int u      = (y < 16) ? y : 47 - y;       // u in [0,31]
    const int A      = 63 - u;                      // tile A index (jmaxA = A >= 32)
    const int par    = (wave >> 1) & 1;
    const int qh     = wave & 1;
    const bool isA   = wave < 4;
    const int tileMine = isA ? A : u;
    const int jmineLow = isA ? A : u;               // low-phase diag guard
    const int colbase  = h * DK;
    const int q0       = tileMine * 64 + qh * 32 + l16;   // qn0 row; qn1 = q0+16

    // Q B-frags [kc][qn]: B[n=q][k=kc*32+quad*8+j]
    s8 qf00, qf10, qf01, qf11;
    {
        const unsigned short* q = Qg + (size_t)q0 * EMB + colbase + quad * 8;
        qf00 = *(const s8*)(q);
        qf10 = *(const s8*)(q + 32);
        qf01 = *(const s8*)(q + (size_t)16 * EMB);
        qf11 = *(const s8*)(q + (size_t)16 * EMB + 32);
    }

    // swizzled K LDS read offsets (shorts)
    const int xr    = (l16 & 7) << 4;
    const int coff0 = ((quad * 16) ^ xr) >> 1;
    const int coff1 = ((64 + quad * 16) ^ xr) >> 1;

    // K staging: 512 thr, 16B each per 64x64 sub-tile; linear LDS dest, pre-swizzled src
    const int srow = tid >> 3;
    const int scol = (((tid & 7) * 16) ^ ((srow & 7) << 4)) >> 1;
    const unsigned short* ksrc = Kg + (size_t)srow * EMB + colbase + scol;

    // V direct-global per-lane base
    const unsigned short* vbase = Vtg + (size_t)(colbase + l16) * SEQ + quad * 8;

    const int iB     = u >> 1;                      // last low pair
    const int ipairs = (65 - u) >> 1;               // total j-pairs (iB+1 < ipairs always)

    // prologue: stage pair 0 (j=0,1; both exist since A >= 32)
    gl2lds16(ksrc,                    &Ks[0][0][wave * 8][0]);
    gl2lds16(ksrc + (size_t)64 * EMB, &Ks[0][1][wave * 8][0]);

    float l0 = 0.0f, l1 = 0.0f;
    f4 o0[4], o1[4];
#pragma unroll
    for (int t = 0; t < 4; ++t) { o0[t] = (f4){0, 0, 0, 0}; o1[t] = (f4){0, 0, 0, 0}; }

    // ---------------- LOW phase ----------------
    for (int i = 0; i <= iB; ++i) {
        __syncthreads();
        const int cur = i & 1;
        if (i + 1 < ipairs) {
            const int je = 2 * (i + 1);
            gl2lds16(ksrc + (size_t)je * 64 * EMB, &Ks[cur ^ 1][0][wave * 8][0]);
            if (je + 1 <= A)
                gl2lds16(ksrc + (size_t)(je + 1) * 64 * EMB, &Ks[cur ^ 1][1][wave * 8][0]);
        }
        const int j = 2 * i + par;
        if (j <= jmineLow) {
            // V prefetch (direct global, L2-resident)
            s8 va0[4], va1[4];
            const unsigned short* vj = vbase + j * 64;
#pragma unroll
            for (int t = 0; t < 4; ++t) {
                va0[t] = *(const s8*)(vj + (size_t)(t * 16) * SEQ);
                va1[t] = *(const s8*)(vj + (size_t)(t * 16) * SEQ + 32);
            }
            // S^T[k][q] = K . Q^T, two q-subtiles share each K fragment
            f4 s0[4] = { {0,0,0,0}, {0,0,0,0}, {0,0,0,0}, {0,0,0,0} };
            f4 s1[4] = { {0,0,0,0}, {0,0,0,0}, {0,0,0,0}, {0,0,0,0} };
            const unsigned short* KsP = &Ks[cur][par][0][0];
            __builtin_amdgcn_s_setprio(1);
#pragma unroll
            for (int t = 0; t < 4; ++t) {
                const int rbase = (t * 16 + l16) * 64;
                s8 kv0 = *(const s8*)&KsP[rbase + coff0];
                s8 kv1 = *(const s8*)&KsP[rbase + coff1];
                s0[t] = __builtin_amdgcn_mfma_f32_16x16x32_bf16(kv0, qf00, s0[t], 0, 0, 0);
                s1[t] = __builtin_amdgcn_mfma_f32_16x16x32_bf16(kv0, qf01, s1[t], 0, 0, 0);
                s0[t] = __builtin_amdgcn_mfma_f32_16x16x32_bf16(kv1, qf10, s0[t], 0, 0, 0);
                s1[t] = __builtin_amdgcn_mfma_f32_16x16x32_bf16(kv1, qf11, s1[t], 0, 0, 0);
            }
            __builtin_amdgcn_s_setprio(0);

            if (j == jmineLow) {                    // diagonal tile: mask k > q
#pragma unroll
                for (int t = 0; t < 4; ++t) {
                    const int kb = j * 64 + t * 16 + quad * 4;
#pragma unroll
                    for (int r = 0; r < 4; ++r) {
                        if (kb + r > q0)      s0[t][r] = -1e30f;
                        if (kb + r > q0 + 16) s1[t][r] = -1e30f;
                    }
                }
            }

            float rs0 = 0.0f, rs1 = 0.0f;
#pragma unroll
            for (int t = 0; t < 4; ++t)
#pragma unroll
                for (int r = 0; r < 4; ++r) {
                    const float p0 = __builtin_amdgcn_exp2f(s0[t][r]);
                    const float p1 = __builtin_amdgcn_exp2f(s1[t][r]);
                    s0[t][r] = p0; rs0 += p0;
                    s1[t][r] = p1; rs1 += p1;
                }
            rs0 += __shfl_xor(rs0, 16);
            rs0 += __shfl_xor(rs0, 32);
            rs1 += __shfl_xor(rs1, 16);
            rs1 += __shfl_xor(rs1, 32);
            l0 += rs0;
            l1 += rs1;

            union { int i[8]; s8 v[2]; } pk0, pk1;
#pragma unroll
            for (int t = 0; t < 4; ++t) {
                pk0.i[t * 2]     = pkbf(s0[t][1], s0[t][0]);
                pk0.i[t * 2 + 1] = pkbf(s0[t][3], s0[t][2]);
                pk1.i[t * 2]     = pkbf(s1[t][1], s1[t][0]);
                pk1.i[t * 2 + 1] = pkbf(s1[t][3], s1[t][2]);
            }

            __builtin_amdgcn_s_setprio(1);
#pragma unroll
            for (int t = 0; t < 4; ++t) {
                o0[t] = __builtin_amdgcn_mfma_f32_16x16x32_bf16(va0[t], pk0.v[0], o0[t], 0, 0, 0);
                o1[t] = __builtin_amdgcn_mfma_f32_16x16x32_bf16(va0[t], pk1.v[0], o1[t], 0, 0, 0);
                o0[t] = __builtin_amdgcn_mfma_f32_16x16x32_bf16(va1[t], pk0.v[1], o0[t], 0, 0, 0);
                o1[t] = __builtin_amdgcn_mfma_f32_16x16x32_bf16(va1[t], pk1.v[1], o1[t], 0, 0, 0);
            }
            __builtin_amdgcn_s_setprio(0);
        }
    }

    // ---------------- TRANSITION: finish tile B, re-arm B-waves ----------------
    if (wave >= 6) {                                // par1 B-waves park partials
        const int hs = (wave - 6) * 2;
        f4* hp0 = (f4*)&mO[hs][lane][0];
        hp0[0] = o0[0]; hp0[1] = o0[1]; hp0[2] = o0[2]; hp0[3] = o0[3];
        mL[hs][lane] = l0;
        f4* hp1 = (f4*)&mO[hs + 1][lane][0];
        hp1[0] = o1[0]; hp1[1] = o1[1]; hp1[2] = o1[2]; hp1[3] = o1[3];
        mL[hs + 1][lane] = l1;
    }
    __syncthreads();
    if (wave == 4 || wave == 5) {                   // par0 B-waves merge + store tile B
        const int hs = (wave - 4) * 2;
        const f4* hp0 = (const f4*)&mO[hs][lane][0];
        const f4* hp1 = (const f4*)&mO[hs + 1][lane][0];
        const float inv0 = 1.0f / (l0 + mL[hs][lane]);
        const float inv1 = 1.0f / (l1 + mL[hs + 1][lane]);
#pragma unroll
        for (int t = 0; t < 4; ++t) {
            f4 a = o0[t] + hp0[t];
            f4 b = o1[t] + hp1[t];
            us4 ov;
#pragma unroll
            for (int r = 0; r < 4; ++r) ov[r] = f2bf(a[r] * inv0);
            *(us4*)&Og[(size_t)q0 * EMB + colbase + t * 16 + quad * 4] = ov;
#pragma unroll
            for (int r = 0; r < 4; ++r) ov[r] = f2bf(b[r] * inv1);
            *(us4*)&Og[(size_t)(q0 + 16) * EMB + colbase + t * 16 + quad * 4] = ov;
        }
    }
    int qrowH, parH;
    if (isA) {
        parH = 0;
        qrowH = A * 64 + qh * 32 + par * 16 + l16;
        if (par) {                                  // continued accumulator -> o0/l0
#pragma unroll
            for (int t = 0; t < 4; ++t) { f4 tmp = o0[t]; o0[t] = o1[t]; o1[t] = tmp; }
            const float tl = l0; l0 = l1; l1 = tl;
            qf00 = qf01; qf10 = qf11;
        }
    } else {
        parH = 1;
        const int b  = wave - 4;
        const int cB = ((b & 1) << 1) | (b >> 1);
        qrowH = A * 64 + cB * 16 + l16;
        const unsigned short* q = Qg + (size_t)qrowH * EMB + colbase + quad * 8;
        qf00 = *(const s8*)(q);
        qf10 = *(const s8*)(q + 32);
#pragma unroll
        for (int t = 0; t < 4; ++t) o0[t] = (f4){0, 0, 0, 0};
        l0 = 0.0f;
    }

    // ---------------- HIGH phase: all 8 waves on tile A ----------------
    for (int i = iB + 1; i < ipairs; ++i) {
        __syncthreads();
        const int cur = i & 1;
        if (i + 1 < ipairs) {
            const int je = 2 * (i + 1);
            gl2lds16(ksrc + (size_t)je * 64 * EMB, &Ks[cur ^ 1][0][wave * 8][0]);
            if (je + 1 <= A)
                gl2lds16(ksrc + (size_t)(je + 1) * 64 * EMB, &Ks[cur ^ 1][1][wave * 8][0]);
        }
        const int j = 2 * i + parH;
        if (j <= A) {
            s8 va0[4], va1[4];
            const unsigned short* vj = vbase + j * 64;
#pragma unroll
            for (int t = 0; t < 4; ++t) {
                va0[t] = *(const s8*)(vj + (size_t)(t * 16) * SEQ);
                va1[t] = *(const s8*)(vj + (size_t)(t * 16) * SEQ + 32);
            }
            f4 sh[4] = { {0,0,0,0}, {0,0,0,0}, {0,0,0,0}, {0,0,0,0} };
            const unsigned short* KsP = &Ks[cur][parH][0][0];
            __builtin_amdgcn_s_setprio(1);
#pragma unroll
            for (int t = 0; t < 4; ++t) {
                const int rbase = (t * 16 + l16) * 64;
                s8 kv0 = *(const s8*)&KsP[rbase + coff0];
                s8 kv1 = *(const s8*)&KsP[rbase + coff1];
                sh[t] = __builtin_amdgcn_mfma_f32_16x16x32_bf16(kv0, qf00, sh[t], 0, 0, 0);
                sh[t] = __builtin_amdgcn_mfma_f32_16x16x32_bf16(kv1, qf10, sh[t], 0, 0, 0);
            }
            __builtin_amdgcn_s_setprio(0);

            if (j == A) {                           // tile-A diagonal
#pragma unroll
                for (int t = 0; t < 4; ++t) {
                    const int kb = j * 64 + t * 16 + quad * 4;
#pragma unroll
                    for (int r = 0; r < 4; ++r)
                        if (kb + r > qrowH) sh[t][r] = -1e30f;
                }
            }

            float rs = 0.0f;
#pragma unroll
            for (int t = 0; t < 4; ++t)
#pragma unroll
                for (int r = 0; r < 4; ++r) {
                    const float p = __builtin_amdgcn_exp2f(sh[t][r]);
                    sh[t][r] = p;
                    rs += p;
                }
            rs += __shfl_xor(rs, 16);
            rs += __shfl_xor(rs, 32);
            l0 += rs;

            union { int i[8]; s8 v[2]; } pkH;
#pragma unroll
            for (int t = 0; t < 4; ++t) {
                pkH.i[t * 2]     = pkbf(sh[t][1], sh[t][0]);
                pkH.i[t * 2 + 1] = pkbf(sh[t][3], sh[t][2]);
            }

            __builtin_amdgcn_s_setprio(1);
#pragma unroll
            for (int t = 0; t < 4; ++t) {
                o0[t] = __builtin_amdgcn_mfma_f32_16x16x32_bf16(va0[t], pkH.v[0], o0[t], 0, 0, 0);
                o0[t] = __builtin_amdgcn_mfma_f32_16x16x32_bf16(va1[t], pkH.v[1], o0[t], 0, 0, 0);
            }
            __builtin_amdgcn_s_setprio(0);
        }
    }

    // ---------------- EPILOGUE: merge tile A quarters ----------------
    if (isA) {                                      // frozen partial (post-swap: o1/l1)
        f4* hp = (f4*)&mO[wave][lane][0];
        hp[0] = o1[0]; hp[1] = o1[1]; hp[2] = o1[2]; hp[3] = o1[3];
        mL[wave][lane] = l1;
    } else {                                        // B high partial
        const int b  = wave - 4;
        const int cB = ((b & 1) << 1) | (b >> 1);
        f4* hp = (f4*)&mO[4 + cB][lane][0];
        hp[0] = o0[0]; hp[1] = o0[1]; hp[2] = o0[2]; hp[3] = o0[3];
        mL[4 + cB][lane] = l0;
    }
    __syncthreads();
    if (isA) {
        const int cOwn = qh * 2 + par;
        const f4* fp = (const f4*)&mO[wave ^ 2][lane][0];
        const f4* bp = (const f4*)&mO[4 + cOwn][lane][0];
        const float inv = 1.0f / (l0 + mL[wave ^ 2][lane] + mL[4 + cOwn][lane]);
#pragma unroll
        for (int t = 0; t < 4; ++t) {
            f4 v = o0[t] + fp[t] + bp[t];
            us4 ov;
#pragma unroll
            for (int r = 0; r < 4; ++r) ov[r] = f2bf(v[r] * inv);
            *(us4*)&Og[(size_t)qrowH * EMB + colbase + t * 16 + quad * 4] = ov;
        }
    }
}

extern "C" void kernel_launch(void* const* d_in, const int* in_sizes, int n_in,
                              void* d_out, int out_size, void* d_ws, size_t ws_size,
                              hipStream_t stream) {
    const float* x  = (const float*)d_in[0];
    const float* Wq = (const float*)d_in[1];
    const float* bq = (const float*)d_in[2];
    const float* Wk = (const float*)d_in[3];
    const float* bk = (const float*)d_in[4];
    const float* Wv = (const float*)d_in[5];
    const float* bv = (const float*)d_in[6];
    const float* Wo = (const float*)d_in[7];
    const float* bo = (const float*)d_in[8];
    float* out = (float*)d_out;

    unsigned short* ws = (unsigned short*)d_ws;
    unsigned short* xb  = ws;                          // [4096][1024]
    unsigned short* Wqb = xb  + (size_t)SEQ * EMB;     // [1024][1024] x4
    unsigned short* Wkb = Wqb + (size_t)EMB * EMB;
    unsigned short* Wvb = Wkb + (size_t)EMB * EMB;
    unsigned short* Wob = Wvb + (size_t)EMB * EMB;
    unsigned short* Qb  = Wob + (size_t)EMB * EMB;     // [4096][1024], pre-scaled 0.125*log2e
    unsigned short* Kb  = Qb  + (size_t)SEQ * EMB;     // [4096][1024]
    unsigned short* Vtb = Kb  + (size_t)SEQ * EMB;     // [1024][4096]  V^T, k-permuted cols
    unsigned short* Ab  = Vtb + (size_t)SEQ * EMB;     // V (pre-transpose), then attn out

    cvt_all<<<8192, 256, 0, stream>>>(x, Wq, Wk, Wv, Wo, xb, Wqb, Wkb, Wvb, Wob);

    qkv_gemm<<<dim3(SEQ / 128, 24), 256, 0, stream>>>(xb, Wqb, Wkb, Wvb, bq, bk, bv, Qb, Kb, Ab);

    transpose_kernel<<<dim3(SEQ / 64, EMB / 64), 256, 0, stream>>>(Ab, Vtb);

    attn_kernel<<<512, 512, 0, stream>>>(Qb, Kb, Vtb, Ab);

    gemm_op<<<dim3(SEQ / 128, EMB / 64), 256, 0, stream>>>(Ab, Wob, bo, out);
}

// Round 3
// 204.855 us; speedup vs baseline: 1.5691x; 1.5691x over previous
//
#include <hip/hip_runtime.h>
#include <hip/hip_bf16.h>
#include <math.h>

#define SEQ 4096
#define EMB 1024
#define NH  16
#define DK  64

typedef __attribute__((ext_vector_type(8))) unsigned short us8;
typedef __attribute__((ext_vector_type(8))) short         s8;
typedef __attribute__((ext_vector_type(4))) unsigned short us4;
typedef __attribute__((ext_vector_type(4))) float          f4;

static __device__ __forceinline__ unsigned short f2bf(float f) {
    union { float f; unsigned u; } v; v.f = f;
    unsigned r = v.u + 0x7FFF + ((v.u >> 16) & 1);
    return (unsigned short)(r >> 16);
}

__device__ __forceinline__ void gl2lds16(const void* g, void* l) {
    __builtin_amdgcn_global_load_lds((const __attribute__((address_space(1))) void*)g,
                                     (__attribute__((address_space(3))) void*)l, 16, 0, 0);
}

// pack two fp32 -> one dword of two truncated bf16 (hi = a, lo = b): one v_perm_b32
__device__ __forceinline__ int pkbf(float a, float b) {
    return (int)__builtin_amdgcn_perm(__float_as_uint(a), __float_as_uint(b), 0x07060302u);
}

// ---------------- fp32 -> bf16 convert, all 5 tensors in one launch ----------------
__global__ void cvt_all(const float* __restrict__ x,
                        const float* __restrict__ w0, const float* __restrict__ w1,
                        const float* __restrict__ w2, const float* __restrict__ w3,
                        unsigned short* __restrict__ xo,
                        unsigned short* __restrict__ o0, unsigned short* __restrict__ o1,
                        unsigned short* __restrict__ o2, unsigned short* __restrict__ o3) {
    const int idx = blockIdx.x * 256 + threadIdx.x;
    const float* in;
    unsigned short* out;
    int off;
    if (idx < (1 << 20)) { in = x; out = xo; off = idx; }
    else {
        const int t = idx - (1 << 20);
        const int w = t >> 18;
        off = t & ((1 << 18) - 1);
        in  = w == 0 ? w0 : (w == 1 ? w1 : (w == 2 ? w2 : w3));
        out = w == 0 ? o0 : (w == 1 ? o1 : (w == 2 ? o2 : o3));
    }
    const float4 v = ((const float4*)in)[off];
    us4 o;
    o[0] = f2bf(v.x); o[1] = f2bf(v.y); o[2] = f2bf(v.z); o[3] = f2bf(v.w);
    ((us4*)out)[off] = o;
}

// ---------------- bf16 64x64 transpose with k-permuted output columns ----------------
// pos(k): k=a*16+b*4+c -> (a>>1)*32 + b*8 + (a&1)*4 + c  (matches attn PV frag layout)
__global__ __launch_bounds__(256) void transpose_kernel(
    const unsigned short* __restrict__ in, unsigned short* __restrict__ out) {
    __shared__ unsigned short t[64][72];
    const int tid = threadIdx.x;
    const int row = tid >> 2, c = (tid & 3) * 16;
    const int gr = blockIdx.x * 64, gc = blockIdx.y * 64;
    const unsigned short* src = in + (size_t)(gr + row) * EMB + gc + c;
    *(us8*)&t[row][c]     = *(const us8*)src;
    *(us8*)&t[row][c + 8] = *(const us8*)(src + 8);
    __syncthreads();
    us8 o0, o1;
#pragma unroll
    for (int j = 0; j < 8; ++j) { o0[j] = t[c + j][row]; o1[j] = t[c + 8 + j][row]; }
    const int a_   = c >> 4;
    const int base = (a_ >> 1) * 32 + (a_ & 1) * 4;
    us4 g0, g1, g2, g3;
#pragma unroll
    for (int i = 0; i < 4; ++i) { g0[i] = o0[i]; g1[i] = o0[4 + i]; g2[i] = o1[i]; g3[i] = o1[4 + i]; }
    unsigned short* dst = out + (size_t)(gc + row) * SEQ + gr + base;
    *(us4*)dst        = g0;
    *(us4*)(dst + 8)  = g1;
    *(us4*)(dst + 16) = g2;
    *(us4*)(dst + 24) = g3;
}

// ---------------- fused QKV projection GEMM, 128x128 tile ----------------
__global__ __launch_bounds__(256) void qkv_gemm(
    const unsigned short* __restrict__ X,
    const unsigned short* __restrict__ Wq, const unsigned short* __restrict__ Wk,
    const unsigned short* __restrict__ Wv,
    const float* __restrict__ bq, const float* __restrict__ bk, const float* __restrict__ bv,
    unsigned short* __restrict__ Qo, unsigned short* __restrict__ Ko, unsigned short* __restrict__ Vo)
{
    __shared__ unsigned short As[128 * 64];
    __shared__ unsigned short Bs[128 * 64];

    const int region = blockIdx.y >> 3;
    const unsigned short* W   = region == 0 ? Wq : (region == 1 ? Wk : Wv);
    const float*         bias = region == 0 ? bq : (region == 1 ? bk : bv);
    unsigned short*      out  = region == 0 ? Qo : (region == 1 ? Ko : Vo);
    const float scale = region == 0 ? 0.18033688011112042f : 1.0f;   // 0.125 * log2(e)

    const int tid  = threadIdx.x;
    const int wave = tid >> 6;
    const int lane = tid & 63;
    const int quad = lane >> 4;
    const int l16  = lane & 15;
    const int wm   = (wave >> 1) * 64;
    const int wn   = (wave & 1) * 64;
    const int bm   = blockIdx.x * 128;
    const int bn   = (blockIdx.y & 7) * 128;

    f4 acc[4][4];
#pragma unroll
    for (int a = 0; a < 4; ++a)
#pragma unroll
        for (int b = 0; b < 4; ++b) acc[a][b] = (f4){0, 0, 0, 0};

    const int rsub = lane >> 3;
    const int gc   = ((lane & 7) ^ rsub) * 8;
    const int swz  = l16 & 7;

    for (int k0 = 0; k0 < EMB; k0 += 64) {
        __syncthreads();
#pragma unroll
        for (int i = 0; i < 4; ++i) {
            const int cb = i * 4 + wave;
            const int r  = cb * 8 + rsub;
            gl2lds16(X + (size_t)(bm + r) * EMB + k0 + gc, &As[cb * 512]);
            gl2lds16(W + (size_t)(bn + r) * EMB + k0 + gc, &Bs[cb * 512]);
        }
        __syncthreads();
#pragma unroll
        for (int kc = 0; kc < 2; ++kc) {
            s8 af[4], bf[4];
#pragma unroll
            for (int t = 0; t < 4; ++t) {
                const int seg = (kc * 4 + quad) ^ swz;
                af[t] = *(const s8*)&As[(wm + t * 16 + l16) * 64 + seg * 8];
                bf[t] = *(const s8*)&Bs[(wn + t * 16 + l16) * 64 + seg * 8];
            }
#pragma unroll
            for (int tm = 0; tm < 4; ++tm)
#pragma unroll
                for (int tn = 0; tn < 4; ++tn)
                    acc[tm][tn] = __builtin_amdgcn_mfma_f32_16x16x32_bf16(af[tm], bf[tn], acc[tm][tn], 0, 0, 0);
        }
    }

#pragma unroll
    for (int tn = 0; tn < 4; ++tn) {
        const int n = bn + wn + tn * 16 + l16;
        const float bv2 = bias[n];
#pragma unroll
        for (int tm = 0; tm < 4; ++tm)
#pragma unroll
            for (int rr = 0; rr < 4; ++rr) {
                const int m = bm + wm + tm * 16 + quad * 4 + rr;
                out[(size_t)m * EMB + n] = f2bf((acc[tm][tn][rr] + bv2) * scale);
            }
    }
}

// ---------------- output projection GEMM, 128x64 tile, fp32 out ----------------
__global__ __launch_bounds__(256) void gemm_op(
    const unsigned short* __restrict__ A, const unsigned short* __restrict__ B,
    const float* __restrict__ bias, float* __restrict__ C)
{
    __shared__ unsigned short As[128 * 64];
    __shared__ unsigned short Bs[64 * 64];

    const int tid  = threadIdx.x;
    const int wave = tid >> 6;
    const int lane = tid & 63;
    const int quad = lane >> 4;
    const int l16  = lane & 15;
    const int wm   = (wave >> 1) * 64;
    const int wn   = (wave & 1) * 32;
    const int bm   = blockIdx.x * 128;
    const int bn   = blockIdx.y * 64;

    f4 acc[4][2];
#pragma unroll
    for (int a = 0; a < 4; ++a) { acc[a][0] = (f4){0,0,0,0}; acc[a][1] = (f4){0,0,0,0}; }

    const int rsub = lane >> 3;
    const int gc   = ((lane & 7) ^ rsub) * 8;
    const int swz  = l16 & 7;

    for (int k0 = 0; k0 < EMB; k0 += 64) {
        __syncthreads();
#pragma unroll
        for (int i = 0; i < 6; ++i) {
            const int cb = i * 4 + wave;
            if (cb < 16) {
                gl2lds16(A + (size_t)(bm + cb * 8 + rsub) * EMB + k0 + gc, &As[cb * 512]);
            } else {
                const int c2 = cb - 16;
                gl2lds16(B + (size_t)(bn + c2 * 8 + rsub) * EMB + k0 + gc, &Bs[c2 * 512]);
            }
        }
        __syncthreads();
#pragma unroll
        for (int kc = 0; kc < 2; ++kc) {
            const int seg = (kc * 4 + quad) ^ swz;
            s8 af[4], bf[2];
#pragma unroll
            for (int t = 0; t < 4; ++t)
                af[t] = *(const s8*)&As[(wm + t * 16 + l16) * 64 + seg * 8];
#pragma unroll
            for (int t = 0; t < 2; ++t)
                bf[t] = *(const s8*)&Bs[(wn + t * 16 + l16) * 64 + seg * 8];
#pragma unroll
            for (int tm = 0; tm < 4; ++tm)
#pragma unroll
                for (int tn = 0; tn < 2; ++tn)
                    acc[tm][tn] = __builtin_amdgcn_mfma_f32_16x16x32_bf16(af[tm], bf[tn], acc[tm][tn], 0, 0, 0);
        }
    }

#pragma unroll
    for (int tn = 0; tn < 2; ++tn) {
        const int n = bn + wn + tn * 16 + l16;
        const float bv2 = bias[n];
#pragma unroll
        for (int tm = 0; tm < 4; ++tm)
#pragma unroll
            for (int rr = 0; rr < 4; ++rr) {
                const int m = bm + wm + tm * 16 + quad * 4 + rr;
                C[(size_t)m * EMB + n] = acc[tm][tn][rr] + bv2;
            }
    }
}

// ---------------- Flash attention (causal): two-phase, V in LDS, aliased merges ------
// Q,K: bf16 [SEQ][EMB] (Q pre-scaled 0.125*log2e). Vt: bf16 [EMB][SEQ], k-permuted cols.
// 512 blocks (XCD-bijective swizzle), 8 waves. Tiles {A=63-u, B=u}. K AND V staged in
// LDS (32KB each, XOR-swizzled, gl2lds w/ pre-swizzled global src) - the V-direct-global
// variant spilled (121MB scratch writes) and regressed 3.4x; this restores the round-1
// data path. LOW phase: waves = {tile}x{qh}x{par}, 32q/wave, 1 K/V read feeds 2 MFMAs.
// TRANSITION: tile B finishes -> par-pair merge through the DEAD pair buffer (iB&1) of
// Ks/Vs (16KB free each), store tile B; B-waves re-arm as tile-A 16-row quarters on the
// odd-j stream; A-waves continue one 16-row quarter (o0 post-swap) on the even stream.
// HIGH phase: 8 waves = 4 quarters x 2 parities, all busy -> utilization 51% -> ~95%.
// EPILOGUE: 3-way merge per quarter through the fully-dead Ks/Vs (64KB free).
// Merge scratch layout [slot][elem][lane] (lane-contiguous, conflict-free scalar ds).
// Fixed-max softmax, exp2 domain, zero-shfl PV, setprio on MFMA clusters (T5).
__global__ __launch_bounds__(512, 4) void attn_kernel(
    const unsigned short* __restrict__ Qg, const unsigned short* __restrict__ Kg,
    const unsigned short* __restrict__ Vtg, unsigned short* __restrict__ Og)
{
    __shared__ unsigned short Ks[2][2][64][64];   // [buf][j&1][row][col^swz]  32KB
    __shared__ unsigned short Vs[2][2][64][64];   //                            32KB

    const int tid  = threadIdx.x;
    const int wave = tid >> 6;
    const int lane = tid & 63;
    const int quad = lane >> 4;
    const int l16  = lane & 15;

    // XCD-bijective swizzle: 512 blocks, 8 XCDs -> 64 consecutive works per XCD (2 heads)
    const int n      = blockIdx.x;
    const int workid = (n & 7) * 64 + (n >> 3);
    const int h      = workid >> 5;
    const int y      = workid & 31;
    const int u      = (y < 16) ? y : 47 - y;       // u in [0,31]
    const int A      = 63 - u;                      // tile A index (>= 32)
    const int par    = (wave >> 1) & 1;
    const int qh     = wave & 1;
    const bool isA   = wave < 4;
    const int tileMine = isA ? A : u;
    const int jmineLow = isA ? A : u;
    const int colbase  = h * DK;
    const int q0       = tileMine * 64 + qh * 32 + l16;   // qn0 row; qn1 = q0+16

    // Q B-frags [kc][qn]: B[n=q][k=kc*32+quad*8+j]
    s8 qf00, qf10, qf01, qf11;
    {
        const unsigned short* q = Qg + (size_t)q0 * EMB + colbase + quad * 8;
        qf00 = *(const s8*)(q);
        qf10 = *(const s8*)(q + 32);
        qf01 = *(const s8*)(q + (size_t)16 * EMB);
        qf11 = *(const s8*)(q + (size_t)16 * EMB + 32);
    }

    // swizzled LDS read offsets (shorts)
    const int xr    = (l16 & 7) << 4;
    const int coff0 = ((quad * 16) ^ xr) >> 1;
    const int coff1 = ((64 + quad * 16) ^ xr) >> 1;

    // staging: 512 thr, 16B each per 64x64 sub-tile; linear LDS dest, pre-swizzled src
    const int srow = tid >> 3;
    const int scol = (((tid & 7) * 16) ^ ((srow & 7) << 4)) >> 1;
    const unsigned short* ksrc = Kg  + (size_t)srow * EMB + colbase + scol;
    const unsigned short* vsrc = Vtg + (size_t)(colbase + srow) * SEQ + scol;

    const int iB     = u >> 1;                      // last low pair
    const int ipairs = (65 - u) >> 1;               // total pairs; iB+1 < ipairs always

    // prologue: stage pair 0 (j=0,1; both exist since A >= 32)
    gl2lds16(ksrc,                    &Ks[0][0][wave * 8][0]);
    gl2lds16(vsrc,                    &Vs[0][0][wave * 8][0]);
    gl2lds16(ksrc + (size_t)64 * EMB, &Ks[0][1][wave * 8][0]);
    gl2lds16(vsrc + 64,               &Vs[0][1][wave * 8][0]);

    float l0 = 0.0f, l1 = 0.0f;
    f4 o0[4], o1[4];
#pragma unroll
    for (int t = 0; t < 4; ++t) { o0[t] = (f4){0, 0, 0, 0}; o1[t] = (f4){0, 0, 0, 0}; }

    // ---------------- LOW phase ----------------
    for (int i = 0; i <= iB; ++i) {
        __syncthreads();
        const int cur = i & 1;
        {                                           // i+1 < ipairs always in low phase
            const int je = 2 * (i + 1);
            gl2lds16(ksrc + (size_t)je * 64 * EMB, &Ks[cur ^ 1][0][wave * 8][0]);
            gl2lds16(vsrc + (size_t)je * 64,       &Vs[cur ^ 1][0][wave * 8][0]);
            if (je + 1 <= A) {
                gl2lds16(ksrc + (size_t)(je + 1) * 64 * EMB, &Ks[cur ^ 1][1][wave * 8][0]);
                gl2lds16(vsrc + (size_t)(je + 1) * 64,       &Vs[cur ^ 1][1][wave * 8][0]);
            }
        }
        const int j = 2 * i + par;
        if (j <= jmineLow) {
            const unsigned short* KsP = &Ks[cur][par][0][0];
            const unsigned short* VsP = &Vs[cur][par][0][0];

            f4 s0[4] = { {0,0,0,0}, {0,0,0,0}, {0,0,0,0}, {0,0,0,0} };
            f4 s1[4] = { {0,0,0,0}, {0,0,0,0}, {0,0,0,0}, {0,0,0,0} };
            __builtin_amdgcn_s_setprio(1);
#pragma unroll
            for (int t = 0; t < 4; ++t) {
                const int rbase = (t * 16 + l16) * 64;
                s8 kv0 = *(const s8*)&KsP[rbase + coff0];
                s8 kv1 = *(const s8*)&KsP[rbase + coff1];
                s0[t] = __builtin_amdgcn_mfma_f32_16x16x32_bf16(kv0, qf00, s0[t], 0, 0, 0);
                s1[t] = __builtin_amdgcn_mfma_f32_16x16x32_bf16(kv0, qf01, s1[t], 0, 0, 0);
                s0[t] = __builtin_amdgcn_mfma_f32_16x16x32_bf16(kv1, qf10, s0[t], 0, 0, 0);
                s1[t] = __builtin_amdgcn_mfma_f32_16x16x32_bf16(kv1, qf11, s1[t], 0, 0, 0);
            }
            __builtin_amdgcn_s_setprio(0);

            if (j == jmineLow) {                    // diagonal tile: mask k > q
#pragma unroll
                for (int t = 0; t < 4; ++t) {
                    const int kb = j * 64 + t * 16 + quad * 4;
#pragma unroll
                    for (int r = 0; r < 4; ++r) {
                        if (kb + r > q0)      s0[t][r] = -1e30f;
                        if (kb + r > q0 + 16) s1[t][r] = -1e30f;
                    }
                }
            }

            float rs0 = 0.0f, rs1 = 0.0f;
#pragma unroll
            for (int t = 0; t < 4; ++t)
#pragma unroll
                for (int r = 0; r < 4; ++r) {
                    const float p0 = __builtin_amdgcn_exp2f(s0[t][r]);
                    const float p1 = __builtin_amdgcn_exp2f(s1[t][r]);
                    s0[t][r] = p0; rs0 += p0;
                    s1[t][r] = p1; rs1 += p1;
                }
            rs0 += __shfl_xor(rs0, 16);
            rs0 += __shfl_xor(rs0, 32);
            rs1 += __shfl_xor(rs1, 16);
            rs1 += __shfl_xor(rs1, 32);
            l0 += rs0;
            l1 += rs1;

            union { int i[8]; s8 v[2]; } pk0, pk1;
#pragma unroll
            for (int t = 0; t < 4; ++t) {
                pk0.i[t * 2]     = pkbf(s0[t][1], s0[t][0]);
                pk0.i[t * 2 + 1] = pkbf(s0[t][3], s0[t][2]);
                pk1.i[t * 2]     = pkbf(s1[t][1], s1[t][0]);
                pk1.i[t * 2 + 1] = pkbf(s1[t][3], s1[t][2]);
            }

            __builtin_amdgcn_s_setprio(1);
#pragma unroll
            for (int t = 0; t < 4; ++t) {
                const int rbase = (t * 16 + l16) * 64;
                s8 va0 = *(const s8*)&VsP[rbase + coff0];
                s8 va1 = *(const s8*)&VsP[rbase + coff1];
                o0[t] = __builtin_amdgcn_mfma_f32_16x16x32_bf16(va0, pk0.v[0], o0[t], 0, 0, 0);
                o1[t] = __builtin_amdgcn_mfma_f32_16x16x32_bf16(va0, pk1.v[0], o1[t], 0, 0, 0);
                o0[t] = __builtin_amdgcn_mfma_f32_16x16x32_bf16(va1, pk0.v[1], o0[t], 0, 0, 0);
                o1[t] = __builtin_amdgcn_mfma_f32_16x16x32_bf16(va1, pk1.v[1], o1[t], 0, 0, 0);
            }
            __builtin_amdgcn_s_setprio(0);
        }
    }

    // ---------------- TRANSITION: finish tile B via dead buffer, re-arm ----------------
    __syncthreads();                                // all reads of pair iB done
    const int bufF = iB & 1;                        // dead pair buffer
    float* mO4 = (float*)&Ks[bufF][0][0][0];        // [4 slots][16 elems][64 lanes] 16KB
    float* mL4 = (float*)&Vs[bufF][0][0][0];        // [4 slots][64 lanes]            1KB
    if (wave >= 6) {                                // par1 B-waves park partials
        const int hs = (wave - 6) * 2;
#pragma unroll
        for (int t = 0; t < 4; ++t)
#pragma unroll
            for (int r = 0; r < 4; ++r) {
                mO4[(hs       * 16 + t * 4 + r) * 64 + lane] = o0[t][r];
                mO4[((hs + 1) * 16 + t * 4 + r) * 64 + lane] = o1[t][r];
            }
        mL4[hs * 64 + lane]       = l0;
        mL4[(hs + 1) * 64 + lane] = l1;
    }
    __syncthreads();
    if (wave == 4 || wave == 5) {                   // par0 B-waves merge + store tile B
        const int hs = (wave - 4) * 2;
        const float inv0 = 1.0f / (l0 + mL4[hs * 64 + lane]);
        const float inv1 = 1.0f / (l1 + mL4[(hs + 1) * 64 + lane]);
#pragma unroll
        for (int t = 0; t < 4; ++t) {
            us4 ov;
#pragma unroll
            for (int r = 0; r < 4; ++r)
                ov[r] = f2bf((o0[t][r] + mO4[(hs * 16 + t * 4 + r) * 64 + lane]) * inv0);
            *(us4*)&Og[(size_t)q0 * EMB + colbase + t * 16 + quad * 4] = ov;
#pragma unroll
            for (int r = 0; r < 4; ++r)
                ov[r] = f2bf((o1[t][r] + mO4[((hs + 1) * 16 + t * 4 + r) * 64 + lane]) * inv1);
            *(us4*)&Og[(size_t)(q0 + 16) * EMB + colbase + t * 16 + quad * 4] = ov;
        }
    }
    int qrowH, parH;
    if (isA) {
        parH = 0;
        qrowH = A * 64 + qh * 32 + par * 16 + l16;
        if (par) {                                  // continued accumulator -> o0/l0
#pragma unroll
            for (int t = 0; t < 4; ++t) { f4 tmp = o0[t]; o0[t] = o1[t]; o1[t] = tmp; }
            const float tl = l0; l0 = l1; l1 = tl;
            qf00 = qf01; qf10 = qf11;
        }
    } else {
        parH = 1;
        const int b  = wave - 4;
        const int cB = ((b & 1) << 1) | (b >> 1);
        qrowH = A * 64 + cB * 16 + l16;
        const unsigned short* q = Qg + (size_t)qrowH * EMB + colbase + quad * 8;
        qf00 = *(const s8*)(q);
        qf10 = *(const s8*)(q + 32);
#pragma unroll
        for (int t = 0; t < 4; ++t) o0[t] = (f4){0, 0, 0, 0};
        l0 = 0.0f;
    }

    // ---------------- HIGH phase: all 8 waves on tile A (4 quarters x 2 par) ------------
    for (int i = iB + 1; i < ipairs; ++i) {
        __syncthreads();                            // also orders merge reads vs prefetch
        const int cur = i & 1;
        if (i + 1 < ipairs) {
            const int je = 2 * (i + 1);
            gl2lds16(ksrc + (size_t)je * 64 * EMB, &Ks[cur ^ 1][0][wave * 8][0]);
            gl2lds16(vsrc + (size_t)je * 64,       &Vs[cur ^ 1][0][wave * 8][0]);
            if (je + 1 <= A) {
                gl2lds16(ksrc + (size_t)(je + 1) * 64 * EMB, &Ks[cur ^ 1][1][wave * 8][0]);
                gl2lds16(vsrc + (size_t)(je + 1) * 64,       &Vs[cur ^ 1][1][wave * 8][0]);
            }
        }
        const int j = 2 * i + parH;
        if (j <= A) {
            const unsigned short* KsP = &Ks[cur][parH][0][0];
            const unsigned short* VsP = &Vs[cur][parH][0][0];

            f4 sh[4] = { {0,0,0,0}, {0,0,0,0}, {0,0,0,0}, {0,0,0,0} };
            __builtin_amdgcn_s_setprio(1);
#pragma unroll
            for (int t = 0; t < 4; ++t) {
                const int rbase = (t * 16 + l16) * 64;
                s8 kv0 = *(const s8*)&KsP[rbase + coff0];
                s8 kv1 = *(const s8*)&KsP[rbase + coff1];
                sh[t] = __builtin_amdgcn_mfma_f32_16x16x32_bf16(kv0, qf00, sh[t], 0, 0, 0);
                sh[t] = __builtin_amdgcn_mfma_f32_16x16x32_bf16(kv1, qf10, sh[t], 0, 0, 0);
            }
            __builtin_amdgcn_s_setprio(0);

            if (j == A) {                           // tile-A diagonal
#pragma unroll
                for (int t = 0; t < 4; ++t) {
                    const int kb = j * 64 + t * 16 + quad * 4;
#pragma unroll
                    for (int r = 0; r < 4; ++r)
                        if (kb + r > qrowH) sh[t][r] = -1e30f;
                }
            }

            float rs = 0.0f;
#pragma unroll
            for (int t = 0; t < 4; ++t)
#pragma unroll
                for (int r = 0; r < 4; ++r) {
                    const float p = __builtin_amdgcn_exp2f(sh[t][r]);
                    sh[t][r] = p;
                    rs += p;
                }
            rs += __shfl_xor(rs, 16);
            rs += __shfl_xor(rs, 32);
            l0 += rs;

            union { int i[8]; s8 v[2]; } pkH;
#pragma unroll
            for (int t = 0; t < 4; ++t) {
                pkH.i[t * 2]     = pkbf(sh[t][1], sh[t][0]);
                pkH.i[t * 2 + 1] = pkbf(sh[t][3], sh[t][2]);
            }

            __builtin_amdgcn_s_setprio(1);
#pragma unroll
            for (int t = 0; t < 4; ++t) {
                const int rbase = (t * 16 + l16) * 64;
                s8 va0 = *(const s8*)&VsP[rbase + coff0];
                s8 va1 = *(const s8*)&VsP[rbase + coff1];
                o0[t] = __builtin_amdgcn_mfma_f32_16x16x32_bf16(va0, pkH.v[0], o0[t], 0, 0, 0);
                o0[t] = __builtin_amdgcn_mfma_f32_16x16x32_bf16(va1, pkH.v[1], o0[t], 0, 0, 0);
            }
            __builtin_amdgcn_s_setprio(0);
        }
    }

    // ---------------- EPILOGUE: merge tile A quarters via dead Ks/Vs --------------------
    __syncthreads();                                // drain last compute reads
    float* mO8 = (float*)&Ks[0][0][0][0];           // [8 slots][16 elems][64 lanes] 32KB
    float* mL8 = (float*)&Vs[0][0][0][0];           // [8 slots][64 lanes]            2KB
    if (isA) {                                      // frozen partial (post-swap: o1/l1)
#pragma unroll
        for (int t = 0; t < 4; ++t)
#pragma unroll
            for (int r = 0; r < 4; ++r)
                mO8[(wave * 16 + t * 4 + r) * 64 + lane] = o1[t][r];
        mL8[wave * 64 + lane] = l1;
    } else {                                        // B high partial
        const int b  = wave - 4;
        const int cB = ((b & 1) << 1) | (b >> 1);
#pragma unroll
        for (int t = 0; t < 4; ++t)
#pragma unroll
            for (int r = 0; r < 4; ++r)
                mO8[((4 + cB) * 16 + t * 4 + r) * 64 + lane] = o0[t][r];
        mL8[(4 + cB) * 64 + lane] = l0;
    }
    __syncthreads();
    if (isA) {
        const int cOwn = qh * 2 + par;
        const float inv = 1.0f / (l0 + mL8[(wave ^ 2) * 64 + lane] + mL8[(4 + cOwn) * 64 + lane]);
#pragma unroll
        for (int t = 0; t < 4; ++t) {
            us4 ov;
#pragma unroll
            for (int r = 0; r < 4; ++r) {
                const float v = o0[t][r]
                              + mO8[((wave ^ 2) * 16 + t * 4 + r) * 64 + lane]
                              + mO8[((4 + cOwn) * 16 + t * 4 + r) * 64 + lane];
                ov[r] = f2bf(v * inv);
            }
            *(us4*)&Og[(size_t)qrowH * EMB + colbase + t * 16 + quad * 4] = ov;
        }
    }
}

extern "C" void kernel_launch(void* const* d_in, const int* in_sizes, int n_in,
                              void* d_out, int out_size, void* d_ws, size_t ws_size,
                              hipStream_t stream) {
    const float* x  = (const float*)d_in[0];
    const float* Wq = (const float*)d_in[1];
    const float* bq = (const float*)d_in[2];
    const float* Wk = (const float*)d_in[3];
    const float* bk = (const float*)d_in[4];
    const float* Wv = (const float*)d_in[5];
    const float* bv = (const float*)d_in[6];
    const float* Wo = (const float*)d_in[7];
    const float* bo = (const float*)d_in[8];
    float* out = (float*)d_out;

    unsigned short* ws = (unsigned short*)d_ws;
    unsigned short* xb  = ws;                          // [4096][1024]
    unsigned short* Wqb = xb  + (size_t)SEQ * EMB;     // [1024][1024] x4
    unsigned short* Wkb = Wqb + (size_t)EMB * EMB;
    unsigned short* Wvb = Wkb + (size_t)EMB * EMB;
    unsigned short* Wob = Wvb + (size_t)EMB * EMB;
    unsigned short* Qb  = Wob + (size_t)EMB * EMB;     // [4096][1024], pre-scaled 0.125*log2e
    unsigned short* Kb  = Qb  + (size_t)SEQ * EMB;     // [4096][1024]
    unsigned short* Vtb = Kb  + (size_t)SEQ * EMB;     // [1024][4096]  V^T, k-permuted cols
    unsigned short* Ab  = Vtb + (size_t)SEQ * EMB;     // V (pre-transpose), then attn out

    cvt_all<<<8192, 256, 0, stream>>>(x, Wq, Wk, Wv, Wo, xb, Wqb, Wkb, Wvb, Wob);

    qkv_gemm<<<dim3(SEQ / 128, 24), 256, 0, stream>>>(xb, Wqb, Wkb, Wvb, bq, bk, bv, Qb, Kb, Ab);

    transpose_kernel<<<dim3(SEQ / 64, EMB / 64), 256, 0, stream>>>(Ab, Vtb);

    attn_kernel<<<512, 512, 0, stream>>>(Qb, Kb, Vtb, Ab);

    gemm_op<<<dim3(SEQ / 128, EMB / 64), 256, 0, stream>>>(Ab, Wob, bo, out);
}